// Round 3
// baseline (513.210 us; speedup 1.0000x reference)
//
#include <hip/hip_runtime.h>
#include <hip/hip_bf16.h>

typedef __attribute__((ext_vector_type(8))) short short8;
typedef __attribute__((ext_vector_type(4))) float f32x4;

__device__ __forceinline__ float bflo(unsigned int u) { return __uint_as_float(u << 16); }
__device__ __forceinline__ float bfhi(unsigned int u) { return __uint_as_float(u & 0xffff0000u); }
__device__ __forceinline__ unsigned int bfrne(float f) {
    unsigned int u = __float_as_uint(f);
    return (u + 0x7fffu + ((u >> 16) & 1u)) >> 16;
}
__device__ __forceinline__ unsigned int packbf2(float lo, float hi) {
    return (bfrne(lo) & 0xffffu) | (bfrne(hi) << 16);
}
__device__ __forceinline__ float fast_rcp(float x) { return __builtin_amdgcn_rcpf(x); }
__device__ __forceinline__ float sigmoidf_fast(float x) { return fast_rcp(1.0f + __expf(-x)); }
__device__ __forceinline__ float tanhf_fast(float x) {
    float e = __expf(2.0f * x);
    return 1.0f - 2.0f * fast_rcp(e + 1.0f);
}
__device__ __forceinline__ short8 pack8(const float* f) {
    short8 r;
#pragma unroll
    for (int i = 0; i < 8; i += 2) {
        unsigned int p = packbf2(f[i], f[i + 1]);
        r[i] = (short)(p & 0xffffu);
        r[i + 1] = (short)(p >> 16);
    }
    return r;
}
__device__ __forceinline__ void unpack8(uint4 v, float* f) {
    const unsigned int* p = (const unsigned int*)&v;
#pragma unroll
    for (int j = 0; j < 4; ++j) { f[2 * j] = bflo(p[j]); f[2 * j + 1] = bfhi(p[j]); }
}

// ---------------------------------------------------------------------------
// Dtype sniffer (round-2 evidence: fires f32 on this harness).
// flags[0]=1 iff emb is f32-backed (bf16 of N(0,1) never has exp 0xFF).
// flags[1]=1 iff edges are int64 (hi-words of indices <100000 all zero).
// ---------------------------------------------------------------------------
__global__ void sniff_kernel(const unsigned short* __restrict__ emb,
                             const int* __restrict__ e32, int* __restrict__ flags)
{
    __shared__ int s_f32, s_nz;
    const int t = threadIdx.x;  // 256
    if (t == 0) { s_f32 = 0; s_nz = 0; }
    __syncthreads();
    int bad = 0;
#pragma unroll 4
    for (int j = 0; j < 64; ++j) {
        unsigned int u = emb[t * 64 + j];
        if (((u >> 7) & 0xFFu) == 0xFFu) bad = 1;
    }
    int nz = 0;
#pragma unroll
    for (int j = 0; j < 8; ++j)
        if (e32[(t * 8 + j) * 2 + 1] != 0) nz = 1;
    if (bad) atomicOr(&s_f32, 1);
    if (nz) atomicOr(&s_nz, 1);
    __syncthreads();
    if (t == 0) { flags[0] = s_f32; flags[1] = s_nz ? 0 : 1; }
}

// ---------------------------------------------------------------------------
// Phase 1: per-node projections.
//   SL[n]=sigmoid(emb.Wl^T)  bf16 plane   (gate in (0,1): bf16 err < 2^-9)
//   SR[n]=sigmoid(emb.Wr^T)  bf16 plane
//   U[n] =emb.Wu^T           f32 plane    (bf16 would risk 0.044 > 0.0389 thr)
// 128x128 tile, 4 waves (2x2), mfma 16x16x32 bf16, B frags in registers.
// ---------------------------------------------------------------------------
__global__ __launch_bounds__(256, 2)
void proj_kernel(const void* __restrict__ embv,
                 const void* __restrict__ w0v, const void* __restrict__ w1v,
                 const void* __restrict__ w2v,
                 unsigned short* __restrict__ SLp,
                 unsigned short* __restrict__ SRp,
                 float* __restrict__ Up,
                 const int* __restrict__ flags, int n_nodes)
{
    const int in_f32 = flags[0];
    const int w = blockIdx.y;
    const void* Wv = (w == 0) ? w0v : (w == 1 ? w1v : w2v);
    const int m0 = blockIdx.x * 128;

    __shared__ unsigned short lds[128 * 136];

    const int tid  = threadIdx.x;
    const int lane = tid & 63;
    const int wave = tid >> 6;
    const int wm   = wave & 1;
    const int wn   = wave >> 1;
    const int l15  = lane & 15;
    const int lgp  = lane >> 4;

    // B fragments: B[k=lgp*8+j][n=l15] = W[n][k]
    short8 bf[4][4];
    if (in_f32) {
        const float* W = (const float*)Wv;
#pragma unroll
        for (int nj = 0; nj < 4; ++nj) {
            const float* wrow = W + (size_t)(wn * 64 + nj * 16 + l15) * 128 + lgp * 8;
#pragma unroll
            for (int s = 0; s < 4; ++s) {
                float f[8];
                *(uint4*)&f[0] = *(const uint4*)(wrow + s * 32);
                *(uint4*)&f[4] = *(const uint4*)(wrow + s * 32 + 4);
                bf[s][nj] = pack8(f);
            }
        }
    } else {
        const unsigned short* W = (const unsigned short*)Wv;
#pragma unroll
        for (int nj = 0; nj < 4; ++nj) {
            const unsigned short* wrow = W + (size_t)(wn * 64 + nj * 16 + l15) * 128 + lgp * 8;
#pragma unroll
            for (int s = 0; s < 4; ++s)
                bf[s][nj] = *(const short8*)(wrow + s * 32);
        }
    }

    // Stage A tile as bf16 into LDS (stride 136 shorts)
    if (in_f32) {
        const float* emb = (const float*)embv;
#pragma unroll
        for (int it = 0; it < 8; ++it) {
            int i = tid + it * 256;
            int row = i >> 4, ch = i & 15;
            int g = m0 + row;
            float f[8] = {0.f, 0.f, 0.f, 0.f, 0.f, 0.f, 0.f, 0.f};
            if (g < n_nodes) {
                const float* src = emb + (size_t)g * 128 + ch * 8;
                *(uint4*)&f[0] = *(const uint4*)src;
                *(uint4*)&f[4] = *(const uint4*)(src + 4);
            }
            *(short8*)(&lds[row * 136 + ch * 8]) = pack8(f);
        }
    } else {
        const unsigned short* emb = (const unsigned short*)embv;
#pragma unroll
        for (int it = 0; it < 4; ++it) {
            int i = tid + it * 256;
            int row = i >> 3, ch = i & 7;
            int g = m0 + row;
            uint4 v = make_uint4(0u, 0u, 0u, 0u);
            if (g < n_nodes) v = *(const uint4*)(emb + (size_t)g * 128 + ch * 8);
            *(uint4*)(&lds[row * 136 + ch * 8]) = v;
        }
    }

    f32x4 acc[4][4];
#pragma unroll
    for (int mi = 0; mi < 4; ++mi)
#pragma unroll
        for (int nj = 0; nj < 4; ++nj)
            acc[mi][nj] = (f32x4){0.f, 0.f, 0.f, 0.f};

    __syncthreads();

#pragma unroll
    for (int s = 0; s < 4; ++s) {
        short8 af[4];
#pragma unroll
        for (int mi = 0; mi < 4; ++mi)
            af[mi] = *(const short8*)(&lds[(wm * 64 + mi * 16 + l15) * 136 + s * 32 + lgp * 8]);
#pragma unroll
        for (int mi = 0; mi < 4; ++mi)
#pragma unroll
            for (int nj = 0; nj < 4; ++nj)
                acc[mi][nj] = __builtin_amdgcn_mfma_f32_16x16x32_bf16(
                    af[mi], bf[s][nj], acc[mi][nj], 0, 0, 0);
    }

    // Epilogue. C/D: col = lane&15, row = (lane>>4)*4 + reg.
    if (w < 2) {
        unsigned short* out = (w == 0) ? SLp : SRp;
        const bool odd = (lane & 1);
#pragma unroll
        for (int mi = 0; mi < 4; ++mi) {
            int nodeBase = m0 + wm * 64 + mi * 16 + lgp * 4;
#pragma unroll
            for (int nj = 0; nj < 4; ++nj) {
                float v0 = sigmoidf_fast(acc[mi][nj][0]);
                float v1 = sigmoidf_fast(acc[mi][nj][1]);
                float v2 = sigmoidf_fast(acc[mi][nj][2]);
                float v3 = sigmoidf_fast(acc[mi][nj][3]);
                float p0 = __shfl_xor(v0, 1), p1 = __shfl_xor(v1, 1);
                float p2 = __shfl_xor(v2, 1), p3 = __shfl_xor(v3, 1);
                unsigned int pkA, pkB; int rA, rB;
                if (!odd) { pkA = packbf2(v0, p0); rA = 0; pkB = packbf2(v1, p1); rB = 1; }
                else      { pkA = packbf2(p2, v2); rA = 2; pkB = packbf2(p3, v3); rB = 3; }
                int colE = wn * 64 + nj * 16 + (l15 & ~1);
                int na = nodeBase + rA, nb = nodeBase + rB;
                if (na < n_nodes) *(unsigned int*)(out + (size_t)na * 128 + colE) = pkA;
                if (nb < n_nodes) *(unsigned int*)(out + (size_t)nb * 128 + colE) = pkB;
            }
        }
    } else {
        // U plane: f32 scalar stores (16-lane 64B segments per reg row)
#pragma unroll
        for (int mi = 0; mi < 4; ++mi) {
            int nodeBase = m0 + wm * 64 + mi * 16 + lgp * 4;
#pragma unroll
            for (int nj = 0; nj < 4; ++nj) {
                int col = wn * 64 + nj * 16 + l15;
#pragma unroll
                for (int r = 0; r < 4; ++r) {
                    int row = nodeBase + r;
                    if (row < n_nodes) Up[(size_t)row * 128 + col] = acc[mi][nj][r];
                }
            }
        }
    }
}

// ---------------------------------------------------------------------------
// Phase 2: per-edge combine. 16 threads/edge, 8 elements each.
//   out[e] = (SL[a] + SR[b]) * tanh(U[a] + U[b] + bias)
// Output dtype: f32 when inputs are f32 (reference output dtype), bf16 else.
// ---------------------------------------------------------------------------
__global__ __launch_bounds__(256)
void edge_kernel(const int* __restrict__ e32,
                 const unsigned short* __restrict__ SL,
                 const unsigned short* __restrict__ SR,
                 const float* __restrict__ U,
                 const void* __restrict__ biasv,
                 void* __restrict__ outv,
                 const int* __restrict__ flags, int n_edges)
{
    const int in_f32 = flags[0];
    const int i64    = flags[1];
    const int tid = threadIdx.x;
    const int e = blockIdx.x * 16 + (tid >> 4);
    if (e >= n_edges) return;
    const int c = (tid & 15) * 8;

    int a, b;
    if (i64) { a = e32[4 * (size_t)e]; b = e32[4 * (size_t)e + 2]; }
    else     { a = e32[2 * (size_t)e]; b = e32[2 * (size_t)e + 1]; }

    float slf[8], srf[8], uaf[8], ubf[8], bif[8];
    unpack8(*(const uint4*)(SL + (size_t)a * 128 + c), slf);
    unpack8(*(const uint4*)(SR + (size_t)b * 128 + c), srf);
    const float* ua = U + (size_t)a * 128 + c;
    const float* ub = U + (size_t)b * 128 + c;
    *(uint4*)&uaf[0] = *(const uint4*)ua;
    *(uint4*)&uaf[4] = *(const uint4*)(ua + 4);
    *(uint4*)&ubf[0] = *(const uint4*)ub;
    *(uint4*)&ubf[4] = *(const uint4*)(ub + 4);
    if (in_f32) {
        const float* bp = (const float*)biasv + c;
        *(uint4*)&bif[0] = *(const uint4*)bp;
        *(uint4*)&bif[4] = *(const uint4*)(bp + 4);
    } else {
        unpack8(*(const uint4*)((const unsigned short*)biasv + c), bif);
    }

    float o[8];
#pragma unroll
    for (int j = 0; j < 8; ++j) {
        float s = slf[j] + srf[j];
        float x = uaf[j] + ubf[j] + bif[j];
        o[j] = s * tanhf_fast(x);
    }

    if (in_f32) {
        float* op = (float*)outv + (size_t)e * 128 + c;
        *(uint4*)op = *(const uint4*)&o[0];
        *(uint4*)(op + 4) = *(const uint4*)&o[4];
    } else {
        unsigned int res[4];
#pragma unroll
        for (int j = 0; j < 4; ++j) res[j] = packbf2(o[2 * j], o[2 * j + 1]);
        *(uint4*)((unsigned short*)outv + (size_t)e * 128 + c) = *(const uint4*)res;
    }
}

extern "C" void kernel_launch(void* const* d_in, const int* in_sizes, int n_in,
                              void* d_out, int out_size, void* d_ws, size_t ws_size,
                              hipStream_t stream)
{
    const void* emb   = d_in[0];
    const int*  edges = (const int*)d_in[1];
    const void* Wl    = d_in[2];
    const void* Wr    = d_in[3];
    const void* Wu    = d_in[4];
    const void* bias  = d_in[5];

    const int n_nodes = in_sizes[0] / 128;
    const int n_edges = in_sizes[1] / 2;

    int* flags = (int*)d_ws;
    const size_t plane_elems = (size_t)n_nodes * 128;
    unsigned short* SLp = (unsigned short*)((char*)d_ws + 256);
    unsigned short* SRp = SLp + plane_elems;                   // +25.6MB
    float*          Up  = (float*)(SRp + plane_elems);         // +51.2MB, f32

    sniff_kernel<<<1, 256, 0, stream>>>((const unsigned short*)emb, edges, flags);

    dim3 g1((n_nodes + 127) / 128, 3);
    proj_kernel<<<g1, 256, 0, stream>>>(emb, Wl, Wr, Wu, SLp, SRp, Up, flags, n_nodes);

    int g2 = (n_edges + 15) / 16;
    edge_kernel<<<g2, 256, 0, stream>>>(edges, SLp, SRp, Up, bias, d_out, flags, n_edges);
}